// Round 1
// baseline (320.186 us; speedup 1.0000x reference)
//
#include <hip/hip_runtime.h>

// GRU stack, hidden_size=1, 6 layers, B=4096, T=2048, D=8.
// One 8-lane group per batch element: lanes 0..5 = layers (skewed pipeline),
// lanes 6..7 idle. Layer l at iteration i handles t = i - l; the previous
// layer's h arrives via __shfl_up(h,1) (it was produced last iteration).
// Lane 0 computes the D=8 input projection inline from x staged in regs
// (8-timestep chunks, double buffered, 1-chunk-ahead prefetch).
//
// All gate math in exp2 form with constants pre-folded:
//   sigmoid(p) = rcp(1 + exp2(c1*p)),  c1 = -log2(e)
//   tanh(y)    = 2*rcp(1 + exp2(c2*y)) - 1,  c2 = -2*log2(e)

#define T_LEN 2048
#define B_SZ  4096

__launch_bounds__(64, 1)
__global__ void gru_scan(const float* __restrict__ x,
                         const float* __restrict__ Wih0,   // [3][8]
                         const float* __restrict__ Wrest,  // [5][3]
                         const float* __restrict__ Whh,    // [6][3]
                         const float* __restrict__ bih,    // [6][3]
                         const float* __restrict__ bhh,    // [6][3]
                         float* __restrict__ out)          // [B]
{
    const int lane = threadIdx.x;      // 0..63 (block = 1 wave)
    const int l    = lane & 7;         // 0..5 layers, 6..7 idle
    const int g    = lane >> 3;        // group within wave
    const int b    = blockIdx.x * 8 + g;

    const float c1 = -1.44269504088896340736f;   // -log2(e)
    const float c2 = 2.0f * c1;

    const int lidx = l < 5 ? l : 5;    // clamp idle lanes to valid rows
    // own-layer hidden-weight constants, pre-scaled
    const float whpr = c1 * Whh[lidx * 3 + 0];
    const float whpz = c1 * Whh[lidx * 3 + 1];
    const float whpn = c2 * Whh[lidx * 3 + 2];
    const float bhpn = c2 * bhh[lidx * 3 + 2];
    // input-side constants (layers >= 1 use fma from neighbor h; the B1*
    // values double as the dot-product inits for lane 0 / layer 0)
    const int ir = lidx >= 1 ? lidx - 1 : 0;
    const float W1r = c1 * Wrest[ir * 3 + 0];
    const float W1z = c1 * Wrest[ir * 3 + 1];
    const float W1n = c2 * Wrest[ir * 3 + 2];
    const float B1r = c1 * (bih[lidx * 3 + 0] + bhh[lidx * 3 + 0]);
    const float B1z = c1 * (bih[lidx * 3 + 1] + bhh[lidx * 3 + 1]);
    const float B1n = c2 *  bih[lidx * 3 + 2];

    // layer-0 projection weights, pre-scaled (uniform across lanes)
    float wr[8], wz[8], wn[8];
    #pragma unroll
    for (int d = 0; d < 8; ++d) {
        wr[d] = c1 * Wih0[d];
        wz[d] = c1 * Wih0[8 + d];
        wn[d] = c2 * Wih0[16 + d];
    }

    const float* xb = x + (size_t)b * T_LEN * 8;

    float4 XA[16], XB[16];   // two 8-timestep x chunks (256 B each)
    float  h = 0.0f;

    auto loadc = [&](float4 (&X)[16], int c) {
        const int t0 = c * 8;
        if (l == 0 && t0 < T_LEN) {
            const float4* p = reinterpret_cast<const float4*>(xb + (size_t)t0 * 8);
            #pragma unroll
            for (int j = 0; j < 16; ++j) X[j] = p[j];
        }
    };

    auto stepc = [&](const float4 (&X)[16], int c) {
        #pragma unroll
        for (int s = 0; s < 8; ++s) {
            const int i = c * 8 + s;
            float nbr = __shfl_up(h, 1);          // prev layer's h at my t

            // layer-0 projection (only lane 0's result is consumed)
            const float4 a  = X[2 * s];
            const float4 b4 = X[2 * s + 1];
            float pr = B1r, pz = B1z, pn = B1n;
            pr = fmaf(a.x,  wr[0], pr); pr = fmaf(a.y,  wr[1], pr);
            pr = fmaf(a.z,  wr[2], pr); pr = fmaf(a.w,  wr[3], pr);
            pr = fmaf(b4.x, wr[4], pr); pr = fmaf(b4.y, wr[5], pr);
            pr = fmaf(b4.z, wr[6], pr); pr = fmaf(b4.w, wr[7], pr);
            pz = fmaf(a.x,  wz[0], pz); pz = fmaf(a.y,  wz[1], pz);
            pz = fmaf(a.z,  wz[2], pz); pz = fmaf(a.w,  wz[3], pz);
            pz = fmaf(b4.x, wz[4], pz); pz = fmaf(b4.y, wz[5], pz);
            pz = fmaf(b4.z, wz[6], pz); pz = fmaf(b4.w, wz[7], pz);
            pn = fmaf(a.x,  wn[0], pn); pn = fmaf(a.y,  wn[1], pn);
            pn = fmaf(a.z,  wn[2], pn); pn = fmaf(a.w,  wn[3], pn);
            pn = fmaf(b4.x, wn[4], pn); pn = fmaf(b4.y, wn[5], pn);
            pn = fmaf(b4.z, wn[6], pn); pn = fmaf(b4.w, wn[7], pn);

            // gate pre-activations, scaled: layer 0 from x-proj, else from nbr
            const float xbr = (l == 0) ? pr : fmaf(nbr, W1r, B1r);
            const float xbz = (l == 0) ? pz : fmaf(nbr, W1z, B1z);
            const float xnp = (l == 0) ? pn : fmaf(nbr, W1n, B1n);

            const float er = __builtin_amdgcn_exp2f(fmaf(whpr, h, xbr));
            const float r  = __builtin_amdgcn_rcpf(1.0f + er);
            const float ez = __builtin_amdgcn_exp2f(fmaf(whpz, h, xbz));
            const float z  = __builtin_amdgcn_rcpf(1.0f + ez);
            const float tn = fmaf(whpn, h, bhpn);
            const float en = __builtin_amdgcn_exp2f(fmaf(r, tn, xnp));
            const float dd = __builtin_amdgcn_rcpf(1.0f + en);
            const float nn = fmaf(2.0f, dd, -1.0f);
            const float hn = fmaf(z, h - nn, nn);

            const int t = i - l;
            h = ((unsigned)t < (unsigned)T_LEN) ? hn : h;  // freeze outside [0,T)
        }
    };

    // 257 chunks cover iterations 0..2055 >= T+5; run 258 (even) as 129 pairs
    loadc(XA, 0);
    loadc(XB, 1);
    #pragma unroll 1
    for (int k = 0; k < 129; ++k) {
        stepc(XA, 2 * k);
        loadc(XA, 2 * k + 2);      // prefetch: consumed next k (after XB)
        stepc(XB, 2 * k + 1);
        loadc(XB, 2 * k + 3);
    }

    if (l == 5) out[b] = h;        // layer-5 h frozen at t = T-1
}

extern "C" void kernel_launch(void* const* d_in, const int* in_sizes, int n_in,
                              void* d_out, int out_size, void* d_ws, size_t ws_size,
                              hipStream_t stream) {
    const float* x     = (const float*)d_in[0];
    const float* Wih0  = (const float*)d_in[1];
    const float* Wrest = (const float*)d_in[2];
    const float* Whh   = (const float*)d_in[3];
    const float* bih   = (const float*)d_in[4];
    const float* bhh   = (const float*)d_in[5];
    float* out = (float*)d_out;

    gru_scan<<<512, 64, 0, stream>>>(x, Wih0, Wrest, Whh, bih, bhh, out);
}